// Round 1
// baseline (2161.443 us; speedup 1.0000x reference)
//
#include <hip/hip_runtime.h>
#include <stdint.h>
#include <stddef.h>

#define NUM_EXPERT 16
#define IN_FEAT 2048
#define OUT_FEAT 8192
#define TOTAL_TOKENS 8192

#define BM 256
#define BN 128
#define BK 32
#define KSTEPS (IN_FEAT / BK)      // 64
#define NT_TILES (OUT_FEAT / BN)   // 64
#define MAX_SLOTS 48               // sum ceil(c_e/256) <= 47; pad to 48 so grid%8==0

typedef __attribute__((ext_vector_type(8))) short short8;     // 8 bf16 = 4 VGPRs
typedef __attribute__((ext_vector_type(4))) float floatx4;
typedef __attribute__((ext_vector_type(4))) uint32_t uintx4;

// pack two fp32 -> two bf16 (round-half-up: +0x8000, take high 16 via v_perm)
__device__ __forceinline__ uint32_t pk_bf16(float a, float b) {
    uint32_t ua = __float_as_uint(a) + 0x8000u;
    uint32_t ub = __float_as_uint(b) + 0x8000u;
    return __builtin_amdgcn_perm(ub, ua, 0x07060302u);
}

// async 16B global->LDS (wave-uniform LDS base + lane*16)
__device__ __forceinline__ void cp16_to_lds(const void* g, void* l) {
    __builtin_amdgcn_global_load_lds(
        (const __attribute__((address_space(1))) uint32_t*)g,
        (__attribute__((address_space(3))) uint32_t*)l, 16, 0, 0);
}

// pre-pass: inp fp32 [8192 x 2048] -> bf16 in ws
__global__ __launch_bounds__(256) void cvt_a_kernel(const float* __restrict__ inp,
                                                    uint16_t* __restrict__ dst) {
    size_t base = ((size_t)blockIdx.x * 256 + threadIdx.x) * 8;
    floatx4 f0 = ((const floatx4*)(inp + base))[0];
    floatx4 f1 = ((const floatx4*)(inp + base))[1];
    uintx4 d;
    d.x = pk_bf16(f0.x, f0.y);
    d.y = pk_bf16(f0.z, f0.w);
    d.z = pk_bf16(f1.x, f1.y);
    d.w = pk_bf16(f1.z, f1.w);
    *(uintx4*)(dst + base) = d;
}

// Grouped GEMM: out[t][o] = sum_k inp[t][k] * W[e][o][k], token groups contiguous.
// LDS layouts (both k-outer, conflict-free):
//   A: chunk c = p*256 + r  (r = tile row 0..255, p = k/8 within BK=32)
//   B: chunk c = p*128 + n  (n = tile col 0..127)
// 512 threads = 8 waves (4m x 2n), wave tile 64x64, acc 4x4 fragments.
template <bool A_IN_WS>
__global__ __launch_bounds__(512, 4)
void moe_gemm(const float* __restrict__ W,
              const float* __restrict__ inp,
              const uint16_t* __restrict__ Abf,
              const int* __restrict__ cnt_raw,
              float* __restrict__ out) {
    // ---- XCD-swizzled 1D grid -> (slot fastest, nt slow) ----
    // nwg = 3072 divisible by 8 -> simple bijective swizzle; consecutive wgids
    // are consecutive m-slots at the same nt => blocks sharing a B-panel are
    // adjacent on the same XCD (L2-hot).
    const int nwg = (int)gridDim.x;
    const int orig = (int)blockIdx.x;
    const int wgid = (orig & 7) * (nwg >> 3) + (orig >> 3);
    const int slot = wgid % MAX_SLOTS;
    const int nt = wgid / MAX_SLOTS;

    // ---- counts dtype autodetect (int32 expected; int64 if JAX x64) ----
    int sum32 = 0;
#pragma unroll
    for (int i = 0; i < NUM_EXPERT; ++i) sum32 += cnt_raw[i];
    const int idxmul = (sum32 == TOTAL_TOKENS) ? 1 : 2;

    // ---- slot -> (expert, local tile) ----
    int e = -1, lt = 0, cnt = 0, row0 = 0;
    {
        int off = 0, tacc = 0;
#pragma unroll
        for (int i = 0; i < NUM_EXPERT; ++i) {
            int c = cnt_raw[i * idxmul];
            int t = (c + BM - 1) >> 8;
            if (e < 0 && slot < tacc + t) {
                e = i; lt = slot - tacc; cnt = c; row0 = off + lt * BM;
            }
            tacc += t; off += c;
        }
    }
    if (e < 0) return;  // slot beyond total tiles

    const int tid = (int)threadIdx.x;
    const int lane = tid & 63;
    const int w = tid >> 6;    // wave 0..7
    const int wm = w & 3;      // wave m-row (64 rows each)
    const int wn = w >> 2;     // wave n-col (64 cols each)
    const int l15 = lane & 15;
    const int l4 = lane >> 4;

    __shared__ uint16_t Abuf[2][BM * BK];  // 2 x 16 KiB
    __shared__ uint16_t Bbuf[2][BN * BK];  // 2 x 8 KiB

    // ---- B staging: thread -> (n = tid&127, p = tid>>7); 8 fp32 = 2 dwordx4 ----
    const int bn_ = tid & (BN - 1);
    const int bp_ = tid >> 7;
    const float* bg = W + ((size_t)e * OUT_FEAT + (size_t)nt * BN + bn_) * IN_FEAT + bp_ * 8;
    const int boff = (bp_ * BN + bn_) * 8;  // uint16-elem offset of this thread's chunk

    // ---- A staging setup ----
    const uint16_t* ag0 = nullptr; const uint16_t* ag1 = nullptr;
    int aoff0 = 0, aoff1 = 0;   // WS path: wave-uniform LDS elem offsets
    const float* ia = nullptr;
    int foff0 = 0, foff1 = 0;   // fallback path: per-thread LDS elem offsets
    if constexpr (A_IN_WS) {
        // global_load_lds inst i covers chunks i*512 + tid
        int c0 = tid, c1 = 512 + tid;
        int r0 = c0 & 255, p0 = c0 >> 8;
        int r1 = c1 & 255, p1 = c1 >> 8;
        int gr0 = min(row0 + r0, TOTAL_TOKENS - 1);
        int gr1 = min(row0 + r1, TOTAL_TOKENS - 1);
        ag0 = Abf + (size_t)gr0 * IN_FEAT + p0 * 8;
        ag1 = Abf + (size_t)gr1 * IN_FEAT + p1 * 8;
        aoff0 = (w * 64) * 8;          // wave-uniform base; lane*16B implicit
        aoff1 = (512 + w * 64) * 8;
    } else {
        int r = tid & 255;
        int pb = (tid >> 8) * 2;       // 0 or 2
        int gr = min(row0 + r, TOTAL_TOKENS - 1);
        ia = inp + (size_t)gr * IN_FEAT + pb * 8;   // 16 consecutive fp32
        foff0 = (pb * 256 + r) * 8;
        foff1 = ((pb + 1) * 256 + r) * 8;
    }

    // ---- fragment chunk indices (constant over K loop) ----
    int aidx[4], bidx[4];
#pragma unroll
    for (int i = 0; i < 4; ++i) aidx[i] = l4 * 256 + wm * 64 + i * 16 + l15;
#pragma unroll
    for (int j = 0; j < 4; ++j) bidx[j] = l4 * 128 + wn * 64 + j * 16 + l15;

    floatx4 acc[4][4] = {};

    // ---- prologue: stage K-tile 0 into buffer 0 ----
    {
        floatx4 b0 = ((const floatx4*)bg)[0];
        floatx4 b1 = ((const floatx4*)bg)[1];
        if constexpr (A_IN_WS) {
            cp16_to_lds(ag0, Abuf[0] + aoff0);
            cp16_to_lds(ag1, Abuf[0] + aoff1);
            ag0 += BK; ag1 += BK;
        } else {
            floatx4 a0 = ((const floatx4*)ia)[0];
            floatx4 a1 = ((const floatx4*)ia)[1];
            floatx4 a2 = ((const floatx4*)ia)[2];
            floatx4 a3 = ((const floatx4*)ia)[3];
            uintx4 da0, da1;
            da0.x = pk_bf16(a0.x, a0.y); da0.y = pk_bf16(a0.z, a0.w);
            da0.z = pk_bf16(a1.x, a1.y); da0.w = pk_bf16(a1.z, a1.w);
            da1.x = pk_bf16(a2.x, a2.y); da1.y = pk_bf16(a2.z, a2.w);
            da1.z = pk_bf16(a3.x, a3.y); da1.w = pk_bf16(a3.z, a3.w);
            *(uintx4*)(Abuf[0] + foff0) = da0;
            *(uintx4*)(Abuf[0] + foff1) = da1;
            ia += BK;
        }
        uintx4 db;
        db.x = pk_bf16(b0.x, b0.y); db.y = pk_bf16(b0.z, b0.w);
        db.z = pk_bf16(b1.x, b1.y); db.w = pk_bf16(b1.z, b1.w);
        *(uintx4*)(Bbuf[0] + boff) = db;
        bg += BK;
        __syncthreads();
    }

    // ---- main loop: stage buf[nxt] first (prefetch), compute buf[cur],
    //      finish staging (cvt+ds_write), ONE barrier per K-step ----
    for (int ks = 0; ks < KSTEPS - 1; ++ks) {
        const int cur = ks & 1, nxt = cur ^ 1;

        // issue next-tile staging before touching LDS for this tile
        floatx4 b0 = ((const floatx4*)bg)[0];
        floatx4 b1 = ((const floatx4*)bg)[1];
        floatx4 a0, a1, a2, a3;
        if constexpr (A_IN_WS) {
            cp16_to_lds(ag0, Abuf[nxt] + aoff0);   // buf[nxt] readers finished
            cp16_to_lds(ag1, Abuf[nxt] + aoff1);   // before previous barrier
            ag0 += BK; ag1 += BK;
        } else {
            a0 = ((const floatx4*)ia)[0];
            a1 = ((const floatx4*)ia)[1];
            a2 = ((const floatx4*)ia)[2];
            a3 = ((const floatx4*)ia)[3];
            ia += BK;
        }
        bg += BK;

        // compute current tile
        const short8* Ach = (const short8*)Abuf[cur];
        const short8* Bch = (const short8*)Bbuf[cur];
        short8 av[4], bv[4];
#pragma unroll
        for (int j = 0; j < 4; ++j) bv[j] = Bch[bidx[j]];
#pragma unroll
        for (int i = 0; i < 4; ++i) av[i] = Ach[aidx[i]];
#pragma unroll
        for (int i = 0; i < 4; ++i)
#pragma unroll
            for (int j = 0; j < 4; ++j)
                acc[i][j] = __builtin_amdgcn_mfma_f32_16x16x32_bf16(av[i], bv[j], acc[i][j], 0, 0, 0);

        // finish staging next tile (HBM latency hidden under ds_read+MFMA)
        if constexpr (!A_IN_WS) {
            uintx4 da0, da1;
            da0.x = pk_bf16(a0.x, a0.y); da0.y = pk_bf16(a0.z, a0.w);
            da0.z = pk_bf16(a1.x, a1.y); da0.w = pk_bf16(a1.z, a1.w);
            da1.x = pk_bf16(a2.x, a2.y); da1.y = pk_bf16(a2.z, a2.w);
            da1.z = pk_bf16(a3.x, a3.y); da1.w = pk_bf16(a3.z, a3.w);
            *(uintx4*)(Abuf[nxt] + foff0) = da0;
            *(uintx4*)(Abuf[nxt] + foff1) = da1;
        }
        {
            uintx4 db;
            db.x = pk_bf16(b0.x, b0.y); db.y = pk_bf16(b0.z, b0.w);
            db.z = pk_bf16(b1.x, b1.y); db.w = pk_bf16(b1.z, b1.w);
            *(uintx4*)(Bbuf[nxt] + boff) = db;
        }
        __syncthreads();  // drains vmcnt (gload_lds) + lgkmcnt (ds_write)
    }

    // ---- tail: compute last K-tile (buffer 1, staged at ks=KSTEPS-2) ----
    {
        const short8* Ach = (const short8*)Abuf[1];
        const short8* Bch = (const short8*)Bbuf[1];
        short8 av[4], bv[4];
#pragma unroll
        for (int j = 0; j < 4; ++j) bv[j] = Bch[bidx[j]];
#pragma unroll
        for (int i = 0; i < 4; ++i) av[i] = Ach[aidx[i]];
#pragma unroll
        for (int i = 0; i < 4; ++i)
#pragma unroll
            for (int j = 0; j < 4; ++j)
                acc[i][j] = __builtin_amdgcn_mfma_f32_16x16x32_bf16(av[i], bv[j], acc[i][j], 0, 0, 0);
    }

    // ---- epilogue: C/D layout col = lane&15, row = (lane>>4)*4 + reg ----
    const int cnt_loc = cnt - lt * BM;  // valid rows in this tile (1..256)
    const size_t col = (size_t)nt * BN + wn * 64 + l15;
#pragma unroll
    for (int i = 0; i < 4; ++i) {
        int rb = wm * 64 + i * 16 + l4 * 4;
#pragma unroll
        for (int reg = 0; reg < 4; ++reg) {
            int r = rb + reg;
            if (r < cnt_loc) {
                float* rp = out + (size_t)(row0 + r) * OUT_FEAT + col;
                rp[0]  = acc[i][0][reg];
                rp[16] = acc[i][1][reg];
                rp[32] = acc[i][2][reg];
                rp[48] = acc[i][3][reg];
            }
        }
    }
}

extern "C" void kernel_launch(void* const* d_in, const int* in_sizes, int n_in,
                              void* d_out, int out_size, void* d_ws, size_t ws_size,
                              hipStream_t stream) {
    const float* inp = (const float*)d_in[0];
    const float* W = (const float*)d_in[1];
    const int* counts = (const int*)d_in[2];
    float* out = (float*)d_out;

    const size_t abytes = (size_t)TOTAL_TOKENS * IN_FEAT * sizeof(uint16_t);  // 32 MiB
    dim3 grid(NT_TILES * MAX_SLOTS);  // 3072 blocks, slot-major after swizzle

    if (ws_size >= abytes) {
        uint16_t* Abf = (uint16_t*)d_ws;
        int nblk = (int)(((size_t)TOTAL_TOKENS * IN_FEAT) / (256 * 8));  // 8192
        cvt_a_kernel<<<nblk, 256, 0, stream>>>(inp, Abf);
        moe_gemm<true><<<grid, 512, 0, stream>>>(W, inp, Abf, counts, out);
    } else {
        moe_gemm<false><<<grid, 512, 0, stream>>>(W, inp, nullptr, counts, out);
    }
}